// Round 5
// baseline (374.467 us; speedup 1.0000x reference)
//
#include <hip/hip_runtime.h>

// Bilinear warp (grid_sample align_corners=True, padding_mode='border').
// src: [B=8, C=16, H=512, W=512] f32, flow: [B, 2, H, W] f32 -> out [B,C,H,W] f32.
//
// R1: XCD swizzle (kept). R2: float2 tap-pairs (kept for fallback path).
// R4 post-mortem: time invariant to traffic (2x), instr count (2x), and MLP
//   => bound by TA/L1 line-transaction throughput of the divergent gather
//   (~25 lines/instr; all visible pipes <22% busy). Fix is structural:
// R5: cooperative LDS staging. Block = 2 rows x 512 cols x 16 ch of one image.
//   Dynamic row-window [ys, ymax+1] (block min/max reduce, cap 16 rows,
//   per-pixel global fallback if out of window). Per channel: coalesced
//   float4 stage -> LDS (issue-early/write-late hides latency under previous
//   channel's compute), then 2 small LDS reads per pixel. Divergence moves
//   from 64B-line TA transactions to 8B-grain LDS banks. Row stride 516
//   floats: rows 16B-aligned, bank-shifted by 4 per row.

#define BB 8
#define CC 16
#define HH 512
#define WW 512
#define HW (HH*WW)

#define NR_MAX  16      // staged row window (rows)
#define LSTRIDE 516     // 512 + 4 pad floats

typedef float f2u __attribute__((ext_vector_type(2), aligned(4)));
typedef float f4u __attribute__((ext_vector_type(4), aligned(16)));

__global__ __launch_bounds__(256) void warp_kernel(
    const float* __restrict__ src,
    const float* __restrict__ flow,
    float* __restrict__ out)
{
    __shared__ float tile[NR_MAX * LSTRIDE];   // 33 KB
    __shared__ int redmn[4], redmx[4];

    // XCD-chunked swizzle over 2048 blocks (8 XCDs x 256): XCD k owns image k,
    // and walks its row-pairs in order -> staging re-reads are same-L2 hits.
    int bid = (int)blockIdx.x;
    int swz = (bid & 7) * 256 + (bid >> 3);
    int b   = swz >> 8;           // image index
    int rp  = swz & 255;          // row-pair index
    int hw0 = rp << 10;           // first pixel of the 2-row tile
    int t   = (int)threadIdx.x;

    const float* fb = flow + (size_t)b * 2 * HW;

    int   yl[4], xl[4], loff[4], inw[4];
    float W00[4], W01[4], W10[4], W11[4];

    #pragma unroll
    for (int p = 0; p < 4; ++p) {
        int hw = hw0 + t + (p << 8);
        int h = hw >> 9, w = hw & (WW - 1);
        float f0 = __builtin_nontemporal_load(fb + hw);
        float f1 = __builtin_nontemporal_load(fb + HW + hw);
        float py = fminf(fmaxf((float)h + f0, 0.0f), (float)(HH - 1));
        float px = fminf(fmaxf((float)w + f1, 0.0f), (float)(WW - 1));
        // Border-exact: clamp low corner to H-2/W-2, let the weight reach 1.
        int y = min((int)py, HH - 2);
        int x = min((int)px, WW - 2);
        float wy = py - (float)y, wx = px - (float)x;
        yl[p] = y; xl[p] = x;
        W00[p] = (1.0f - wy) * (1.0f - wx);
        W01[p] = (1.0f - wy) * wx;
        W10[p] = wy * (1.0f - wx);
        W11[p] = wy * wx;
    }

    // Block-wide min/max of yl -> dynamic staging window.
    int mn = min(min(yl[0], yl[1]), min(yl[2], yl[3]));
    int mx = max(max(yl[0], yl[1]), max(yl[2], yl[3]));
    #pragma unroll
    for (int off = 32; off; off >>= 1) {
        mn = min(mn, __shfl_xor(mn, off));
        mx = max(mx, __shfl_xor(mx, off));
    }
    int wid = t >> 6;
    if ((t & 63) == 0) { redmn[wid] = mn; redmx[wid] = mx; }
    __syncthreads();
    int ys = min(min(redmn[0], redmn[1]), min(redmn[2], redmn[3]));
    int ye = max(max(redmx[0], redmx[1]), max(redmx[2], redmx[3]));
    int nrows = min(ye + 2 - ys, NR_MAX);       // rows ys .. ys+nrows-1 (<=511)
    int ntot  = nrows << 9;                     // floats to stage per channel

    #pragma unroll
    for (int p = 0; p < 4; ++p) {
        loff[p] = (yl[p] - ys) * LSTRIDE + xl[p];
        inw[p]  = (yl[p] - ys) <= (nrows - 2);  // rows yl, yl+1 both staged
    }

    const float* sb = src + (size_t)b * CC * HW;
    float*       ob = out + (size_t)b * CC * HW;
    int t4 = t << 2;

    const float* sc = sb + (ys << 9);   // staging base (row ys), advanced per channel
    const float* sg = sb;               // fallback base, advanced per channel
    float*       oc = ob;

    for (int c = 0; c < CC; ++c) {
        // Issue ALL staging loads before the barrier: they overlap the
        // previous channel's compute (issue-early / write-late).
        f4u sr[8];
        #pragma unroll
        for (int k = 0; k < 8; ++k) {
            int i = t4 + (k << 10);
            if (i < ntot) sr[k] = *reinterpret_cast<const f4u*>(sc + i);
        }
        if (c) __syncthreads();         // previous compute done reading tile
        #pragma unroll
        for (int k = 0; k < 8; ++k) {
            int i = t4 + (k << 10);
            if (i < ntot) {
                int r = i >> 9, cl = i & (WW - 1);
                *reinterpret_cast<f4u*>(&tile[r * LSTRIDE + cl]) = sr[k];
            }
        }
        __syncthreads();

        #pragma unroll
        for (int p = 0; p < 4; ++p) {
            float v;
            if (inw[p]) {
                f2u a = *reinterpret_cast<const f2u*>(&tile[loff[p]]);
                f2u d = *reinterpret_cast<const f2u*>(&tile[loff[p] + LSTRIDE]);
                v = a.x * W00[p] + a.y * W01[p] + d.x * W10[p] + d.y * W11[p];
            } else {
                // Rare (window overflow): direct global tap-pair gather.
                int u0 = (yl[p] << 9) + xl[p];
                f2u a = *reinterpret_cast<const f2u*>(sg + u0);
                f2u d = *reinterpret_cast<const f2u*>(sg + u0 + WW);
                v = a.x * W00[p] + a.y * W01[p] + d.x * W10[p] + d.y * W11[p];
            }
            __builtin_nontemporal_store(v, oc + hw0 + t + (p << 8));
        }
        sc += HW; sg += HW; oc += HW;
    }
}

extern "C" void kernel_launch(void* const* d_in, const int* in_sizes, int n_in,
                              void* d_out, int out_size, void* d_ws, size_t ws_size,
                              hipStream_t stream) {
    const float* src  = (const float*)d_in[0];
    const float* flow = (const float*)d_in[1];
    float* out = (float*)d_out;

    dim3 block(256);
    dim3 grid(BB * (HH / 2));                // 2048 blocks: 8 images x 256 row-pairs
    warp_kernel<<<grid, block, 0, stream>>>(src, flow, out);
}

// Round 6
// 284.358 us; speedup vs baseline: 1.3169x; 1.3169x over previous
//
#include <hip/hip_runtime.h>

// Bilinear warp (grid_sample align_corners=True, padding_mode='border').
// src: [B=8, C=16, H=512, W=512] f32, flow: [B, 2, H, W] f32 -> out [B,C,H,W] f32.
//
// R1: XCD-chunked blockIdx swizzle (kept) — halved HBM fetch, time flat.
// R2: float2 tap-pair gathers (kept) — 64->32 gather instrs.
// R5: LDS staging REGRESSED (218us): occupancy 11%, 7.8M LDS bank conflicts,
//     more VMEM instrs than the gather it replaced. Reverted.
// R6: R4 structure + __launch_bounds__(256, 4). R4's VGPR came back 40 =>
//     regalloc could NOT have kept 32 f2u loads in flight (needs 64 dest
//     VGPRs); the MLP experiment was invalidated by the default register
//     budget. min-waves=4 licenses 128 VGPRs so all 32 gathers stay live
//     across the sched_barrier: in-flight loads/CU ~230 -> ~512.
//     Validity gate: VGPR_Count must rise to ~100+. If it does and time is
//     still ~120us, latency/MLP is disproven -> TA line-transaction roofline.

#define BB 8
#define CC 16
#define HH 512
#define WW 512

// 8-byte vector with declared 4-byte alignment so the compiler may emit a
// single global_load_dwordx2 at any dword-aligned address.
typedef float f2u __attribute__((ext_vector_type(2), aligned(4)));

__global__ __launch_bounds__(256, 4) void warp_kernel(
    const float* __restrict__ src,
    const float* __restrict__ flow,
    float* __restrict__ out)
{
    const int HW = HH * WW;              // 262144
    const int NWG = (BB * HW) / 256;     // 8192 workgroups, divisible by 8
    const int CHUNK = NWG / 8;           // 1024 per XCD

    // bijective XCD-chunked swizzle: XCD k gets work items [k*CHUNK, (k+1)*CHUNK)
    int bid = (int)blockIdx.x;
    int swz = (bid & 7) * CHUNK + (bid >> 3);
    int idx = swz * 256 + (int)threadIdx.x;   // pixel index in [0, B*H*W)

    int b  = idx >> 18;          // / (512*512)
    int hw = idx & (HW - 1);
    int h  = hw >> 9;            // / 512
    int w  = hw & (WW - 1);

    const float* fb = flow + (size_t)b * 2 * HW;
    float f0 = __builtin_nontemporal_load(fb + hw);        // y displacement
    float f1 = __builtin_nontemporal_load(fb + HW + hw);   // x displacement

    float py = fminf(fmaxf((float)h + f0, 0.0f), (float)(HH - 1));
    float px = fminf(fmaxf((float)w + f1, 0.0f), (float)(WW - 1));

    // Border-exact reformulation: clamp the low corner to H-2/W-2 and let the
    // fractional weight reach 1. At py=511: yl=510, wy=1 -> full weight on
    // row 511 (identical result). No per-tap clamps needed.
    int yl = min((int)py, HH - 2);       // py >= 0, so (int) == floor
    int xl = min((int)px, WW - 2);
    float wy = py - (float)yl;
    float wx = px - (float)xl;

    float w00 = (1.0f - wy) * (1.0f - wx);
    float w01 = (1.0f - wy) * wx;
    float w10 = wy * (1.0f - wx);
    float w11 = wy * wx;

    int u0 = yl * WW + xl;               // low row, cols [xl, xl+1]
    int u1 = u0 + WW;                    // high row (yl+1 <= 511)

    const float* sb = src + (size_t)b * CC * HW;
    float*       ob = out + (size_t)b * CC * HW;

    // Phase 1: issue ALL 32 independent gathers (2 per channel). With the
    // 128-VGPR budget from launch_bounds(256,4), all results stay live.
    f2u r0[CC], r1[CC];
    #pragma unroll
    for (int c = 0; c < CC; ++c) {
        const float* sc = sb + c * HW;
        r0[c] = *reinterpret_cast<const f2u*>(sc + u0);   // {v00, v01}
        r1[c] = *reinterpret_cast<const f2u*>(sc + u1);   // {v10, v11}
    }
    // Pin the schedule: no compute sinks above, no loads sink below.
    __builtin_amdgcn_sched_barrier(0);

    // Phase 2: weighted sums + coalesced nontemporal stores. Consumption is
    // oldest-first, so vmcnt waits stay shallow while newer loads fly.
    #pragma unroll
    for (int c = 0; c < CC; ++c) {
        float v = r0[c].x * w00 + r0[c].y * w01
                + r1[c].x * w10 + r1[c].y * w11;
        __builtin_nontemporal_store(v, ob + c * HW + hw);
    }
}

extern "C" void kernel_launch(void* const* d_in, const int* in_sizes, int n_in,
                              void* d_out, int out_size, void* d_ws, size_t ws_size,
                              hipStream_t stream) {
    const float* src  = (const float*)d_in[0];
    const float* flow = (const float*)d_in[1];
    float* out = (float*)d_out;

    const int n_pix = BB * HH * WW;          // 2,097,152
    dim3 block(256);
    dim3 grid(n_pix / 256);                  // 8192 blocks (exact)
    warp_kernel<<<grid, block, 0, stream>>>(src, flow, out);
}